// Round 3
// baseline (244.944 us; speedup 1.0000x reference)
//
#include <hip/hip_runtime.h>
#include <math.h>

// Problem constants (fixed shapes per reference)
constexpr int NPB = 15;   // NUM_PROB_BINS
constexpr int NC  = 8;    // NUM_CLASSES
constexpr int NNB = 9;    // NUM_NEIGHBOR_CLASSES (3x3)
constexpr int Bn  = 16;
constexpr int Hc  = 512;
constexpr int Wc  = 512;

// Tile: 64x32 outputs per 1024-thread block, +1 halo ring.
// Halo redundancy 66*34/2048 = 1.096.
// LDS = 71808 + 4320 = 76128 B -> 2 blocks/CU -> 32 waves/CU (100% occ cap).
constexpr int TX = 64, TY = 32;
constexpr int HX = TX + 2;  // 66
constexpr int HY = TY + 2;  // 34
constexpr int NT = 1024;
constexpr int GX = Wc / TX;           // 8
constexpr int GY = Hc / TY;           // 16
constexpr int NBLK = GX * GY * Bn;    // 2048

typedef float f32x2 __attribute__((ext_vector_type(2)));

// fp32-correctly-rounded-almost-always exp for d in [-90, 0].
// Half-octave reduction, single constant (|k|<=260 -> kd*ulp(ln2/2) < 6e-15
// rel). Degree-8 Taylor on |r| <= ln2/4: rel err 3.7e-13 -> non-CR fraction
// ~1e-5 -> expected bin flips ~1e-4 over all 40M calls. Validated: absmax
// stayed at the bf16 comparison floor (no flips). NUMERICS FROZEN.
__device__ __forceinline__ float exp_f32_cr(float df) {
    const double d = (double)df;
    double t  = d * 2.8853900817779268;            // 2*log2(e)
    double kd = rint(t);
    int    k  = (int)kd;
    double r  = fma(kd, -0.34657359027997265, d);  // nearest-double -(ln2/2)
    double p = 2.48015873015873016e-5;             // 1/8!
    p = fma(p, r, 1.98412698412698413e-4);
    p = fma(p, r, 1.38888888888888889e-3);
    p = fma(p, r, 8.33333333333333333e-3);
    p = fma(p, r, 4.16666666666666666e-2);
    p = fma(p, r, 1.66666666666666667e-1);
    p = fma(p, r, 0.5);
    p = fma(p, r, 1.0);
    p = fma(p, r, 1.0);
    double v = (k & 1) ? p * 1.4142135623730951 : p;
    // ldexp by k>>1 via exponent add (v in [0.7,1.5], stays normal)
    long long bits = __double_as_longlong(v) + ((long long)(k >> 1) << 52);
    return (float)__longlong_as_double(bits);
}

// Reciprocal to ~1 ulp of double: rcp_f32 seed + 2 fp64 Newton iters.
// fl32(x * rcp64(s)) != fl32(x/s) with probability ~2^-29 — no bin flips.
__device__ __forceinline__ double rcp64(float s) {
    double dS = (double)s;
    double r  = (double)__builtin_amdgcn_rcpf(s);
    r = r * fma(-dS, r, 2.0);
    r = r * fma(-dS, r, 2.0);
    return r;
}

__global__ __launch_bounds__(NT, 8)  // cap VGPR at 64 so LDS-limited 2 blocks/CU are resident
void nectar_kernel(const float* __restrict__ logits,
                   const float* __restrict__ vf,
                   float* __restrict__ out)
{
    __shared__ __align__(16) float sP[NC][HY][HX];  // halo softmax probs: 71808 B
    __shared__ float sVF[NC * NNB * NPB];           // calibration table:   4320 B
    // total 76128 B -> 2 blocks/CU, 32 waves/CU

    const int tid = threadIdx.x;

    // XCD swizzle: each XCD owns 32 consecutive semantic tiles (a 512x128
    // band of one image) so halo re-reads hit that XCD's own L2.
    const int h    = blockIdx.x;            // 0..2047
    const int sg   = h >> 8;                // supergroup of 256
    const int xcd  = h & 7;
    const int slot = (h >> 3) & 31;
    const int sem  = (sg << 8) + (xcd << 5) + slot;

    const int bx = sem & (GX - 1);
    const int by = (sem >> 3) & (GY - 1);
    const int b  = sem >> 7;
    const int x0 = bx * TX;
    const int y0 = by * TY;

    for (int i = tid; i < NC * NNB * NPB; i += NT) sVF[i] = vf[i];

    const size_t plane = (size_t)Hc * Wc;
    const float* src = logits + (size_t)b * NC * plane;

    // ---- Phase 1: softmax for every halo pixel, restructured as PAIR tasks.
    // 34 rows x 32 pairs = 1088 pair-tasks cover halo cols 1..64 (pairs start
    // at even gx -> aligned dwordx2 loads); 34 x 2 = 68 single-tasks cover
    // cols 0 and 65. Two INTERLEAVED softmax chains per pair-thread double
    // the fp64-exp ILP the scheduler can use (R2 showed VGPR=20 serialized
    // the chain; this forces ~2x chains live). Per-pixel fp32 op ORDER is
    // byte-identical to the scalar path -> bit-identical output.
    auto do_pair = [&](int t) {
        const int row = t >> 5;             // 0..33
        const int k   = t & 31;
        const int lx0 = 2 * k + 1;          // odd halo col 1..63
        const int gy  = y0 + row - 1;
        const int gx0 = x0 + 2 * k;         // even -> 8B-aligned, always in [0,510]
        if ((unsigned)gy < (unsigned)Hc) {
            const float* p0 = src + (size_t)gy * Wc + gx0;
            f32x2 w[NC];
            #pragma unroll
            for (int c = 0; c < NC; c++) w[c] = *(const f32x2*)(p0 + (size_t)c * plane);
            float mA = w[0].x, mB = w[0].y;
            #pragma unroll
            for (int c = 1; c < NC; c++) { mA = fmaxf(mA, w[c].x); mB = fmaxf(mB, w[c].y); }
            float SA = 0.0f, SB = 0.0f;
            float eA[NC], eB[NC];
            #pragma unroll
            for (int c = 0; c < NC; c++) {
                eA[c] = exp_f32_cr(w[c].x - mA);
                eB[c] = exp_f32_cr(w[c].y - mB);
                SA = SA + eA[c];            // sequential accumulation (order sacred)
                SB = SB + eB[c];
            }
            double rA = rcp64(SA);
            double rB = rcp64(SB);
            #pragma unroll
            for (int c = 0; c < NC; c++) {
                sP[c][row][lx0]     = (float)((double)eA[c] * rA);
                sP[c][row][lx0 + 1] = (float)((double)eB[c] * rB);
            }
        } else {
            #pragma unroll
            for (int c = 0; c < NC; c++) {
                sP[c][row][lx0]     = 0.0f;
                sP[c][row][lx0 + 1] = 0.0f;
            }
        }
    };

    do_pair(tid);                           // tasks 0..1023 (rows 0..31)
    if (tid < 64) {
        do_pair(tid + 1024);                // tasks 1024..1087 (rows 32..33)
    } else if (tid < 64 + 68) {
        // single tasks: halo cols 0 and 65
        const int s    = tid - 64;          // 0..67
        const int row  = s >> 1;            // 0..33
        const int side = s & 1;
        const int lx   = side ? (HX - 1) : 0;
        const int gy   = y0 + row - 1;
        const int gx   = x0 + lx - 1;
        if ((unsigned)gy < (unsigned)Hc && (unsigned)gx < (unsigned)Wc) {
            const float* p = src + (size_t)gy * Wc + gx;
            float v[NC];
            #pragma unroll
            for (int c = 0; c < NC; c++) v[c] = p[(size_t)c * plane];
            float m = v[0];
            #pragma unroll
            for (int c = 1; c < NC; c++) m = fmaxf(m, v[c]);
            float S = 0.0f;
            #pragma unroll
            for (int c = 0; c < NC; c++) {
                v[c] = exp_f32_cr(v[c] - m);
                S = S + v[c];
            }
            double rS = rcp64(S);
            #pragma unroll
            for (int c = 0; c < NC; c++)
                sP[c][row][lx] = (float)((double)v[c] * rS);
        } else {
            #pragma unroll
            for (int c = 0; c < NC; c++) sP[c][row][lx] = 0.0f;
        }
    }
    __syncthreads();

    // ---- Phase 2: each thread -> 2 horizontally adjacent outputs.
    // lx2 even + row stride 66 dwords (even) -> all window reads are
    // 8B-aligned f32x2 (ds_read_b64), output stores are dwordx2.
    const int lx2 = (tid & 31) * 2;         // 0,2,..,62
    const int oy  = tid >> 5;               // 0..31
    const int gx2 = x0 + lx2;
    const int gy  = y0 + oy;

    const double C9 = 0.1111111111111111111;    // nearest double to 1/9

    float calL[NC], calR[NC];
    float s0 = 0.0f, s1 = 0.0f;
    #pragma unroll
    for (int c = 0; c < NC; c++) {
        const float* base = &sP[c][oy][lx2];    // halo cols lx2..lx2+3, rows oy..oy+2
        f32x2 u0 = *(const f32x2*)(base);
        f32x2 v0 = *(const f32x2*)(base + 2);
        f32x2 u1 = *(const f32x2*)(base + HX);
        f32x2 v1 = *(const f32x2*)(base + HX + 2);
        f32x2 u2 = *(const f32x2*)(base + 2 * HX);
        f32x2 v2 = *(const f32x2*)(base + 2 * HX + 2);
        // Strict left-to-right sequential add chains (row-major (dy,dx)
        // order) — reassociation would flip bins, order is sacred.
        // Left output window: cols {0,1,2}; right output: cols {1,2,3}.
        float a0 = ((((((((u0.x + u0.y) + v0.x) + u1.x) + u1.y) + v1.x) + u2.x) + u2.y) + v2.x);
        float a1 = ((((((((u0.y + v0.x) + v0.y) + u1.y) + v1.x) + v1.y) + u2.y) + v2.x) + v2.y);

        float nm0 = (float)((double)a0 * C9);   // fl32(a/9) via double mul
        float nm1 = (float)((double)a1 * C9);
        int lb0 = (int)(nm0 * 9.0f);            // trunc == floor (nm >= 0)
        int lb1 = (int)(nm1 * 9.0f);
        lb0 = lb0 > NNB - 1 ? NNB - 1 : lb0;
        lb1 = lb1 > NNB - 1 ? NNB - 1 : lb1;
        int pb0 = (int)(u1.y * 15.0f);          // center of left window
        int pb1 = (int)(v1.x * 15.0f);          // center of right window
        pb0 = pb0 > NPB - 1 ? NPB - 1 : pb0;
        pb1 = pb1 > NPB - 1 ? NPB - 1 : pb1;
        calL[c] = sVF[(c * NNB + lb0) * NPB + pb0];
        calR[c] = sVF[(c * NNB + lb1) * NPB + pb1];
        s0 = s0 + calL[c];                      // sequential class sum
        s1 = s1 + calR[c];
    }
    if (s0 == 0.0f) s0 = 1.0f;
    if (s1 == 0.0f) s1 = 1.0f;

    // Final normalize is NOT bin-critical (bf16-floor comparison): fp32
    // rcp + 1 Newton, rel err ~1e-7 << threshold.
    float q0 = __builtin_amdgcn_rcpf(s0);
    q0 = q0 * fmaf(-s0, q0, 2.0f);
    float q1 = __builtin_amdgcn_rcpf(s1);
    q1 = q1 * fmaf(-s1, q1, 2.0f);

    // Nontemporal stores: output is write-once/never-read — keep it from
    // evicting the L3-resident logits.
    float* dst = out + (size_t)b * NC * plane + (size_t)gy * Wc + gx2;
    #pragma unroll
    for (int c = 0; c < NC; c++) {
        f32x2 o;
        o.x = calL[c] * q0;
        o.y = calR[c] * q1;
        __builtin_nontemporal_store(o, (f32x2*)(dst + (size_t)c * plane));
    }
}

extern "C" void kernel_launch(void* const* d_in, const int* in_sizes, int n_in,
                              void* d_out, int out_size, void* d_ws, size_t ws_size,
                              hipStream_t stream) {
    const float* logits = (const float*)d_in[0];
    const float* vf     = (const float*)d_in[1];
    float* out          = (float*)d_out;

    nectar_kernel<<<dim3(NBLK), dim3(NT), 0, stream>>>(logits, vf, out);
}

// Round 4
// 232.916 us; speedup vs baseline: 1.0516x; 1.0516x over previous
//
#include <hip/hip_runtime.h>
#include <math.h>

// Problem constants (fixed shapes per reference)
constexpr int NPB = 15;   // NUM_PROB_BINS
constexpr int NC  = 8;    // NUM_CLASSES
constexpr int NNB = 9;    // NUM_NEIGHBOR_CLASSES (3x3)
constexpr int Bn  = 16;
constexpr int Hc  = 512;
constexpr int Wc  = 512;

// Tile: 64x32 outputs per 1024-thread block, +1 halo ring.
// Halo redundancy 66*34/2048 = 1.096.
// LDS = 71808 + 4320 = 76128 B -> 2 blocks/CU -> 32 waves/CU.
constexpr int TX = 64, TY = 32;
constexpr int HX = TX + 2;  // 66
constexpr int HY = TY + 2;  // 34
constexpr int NT = 1024;
constexpr int GX = Wc / TX;           // 8
constexpr int GY = Hc / TY;           // 16
constexpr int NBLK = GX * GY * Bn;    // 2048
constexpr int NHALO = HX * HY;        // 2244

typedef float f32x2 __attribute__((ext_vector_type(2)));

// fp32-correctly-rounded-almost-always exp for d in [-90, 0].
// Half-octave reduction, single constant (|k|<=260 -> kd*ulp(ln2/2) < 6e-15
// rel). Degree-8 Taylor on |r| <= ln2/4: rel err 3.7e-13 -> non-CR fraction
// ~1e-5 -> expected bin flips ~1e-4 over all 40M calls. Validated: absmax
// stayed at the bf16 comparison floor (no flips). NUMERICS FROZEN.
__device__ __forceinline__ float exp_f32_cr(float df) {
    const double d = (double)df;
    double t  = d * 2.8853900817779268;            // 2*log2(e)
    double kd = rint(t);
    int    k  = (int)kd;
    double r  = fma(kd, -0.34657359027997265, d);  // nearest-double -(ln2/2)
    double p = 2.48015873015873016e-5;             // 1/8!
    p = fma(p, r, 1.98412698412698413e-4);
    p = fma(p, r, 1.38888888888888889e-3);
    p = fma(p, r, 8.33333333333333333e-3);
    p = fma(p, r, 4.16666666666666666e-2);
    p = fma(p, r, 1.66666666666666667e-1);
    p = fma(p, r, 0.5);
    p = fma(p, r, 1.0);
    p = fma(p, r, 1.0);
    double v = (k & 1) ? p * 1.4142135623730951 : p;
    // ldexp by k>>1 via exponent add (v in [0.7,1.5], stays normal)
    long long bits = __double_as_longlong(v) + ((long long)(k >> 1) << 52);
    return (float)__longlong_as_double(bits);
}

// Reciprocal to ~1 ulp of double: rcp_f32 seed + 2 fp64 Newton iters.
// fl32(x * rcp64(s)) != fl32(x/s) with probability ~2^-29 — no bin flips.
// NUMERICS FROZEN.
__device__ __forceinline__ double rcp64(float s) {
    double dS = (double)s;
    double r  = (double)__builtin_amdgcn_rcpf(s);
    r = r * fma(-dS, r, 2.0);
    r = r * fma(-dS, r, 2.0);
    return r;
}

__global__ __launch_bounds__(NT, 8)  // 8 waves/EU -> 2 blocks/CU, VGPR cap 64
void nectar_kernel(const float* __restrict__ logits,
                   const float* __restrict__ vf,
                   float* __restrict__ out)
{
    __shared__ __align__(16) float sP[NC][HY][HX];  // halo softmax probs: 71808 B
    __shared__ float sVF[NC * NNB * NPB];           // calibration table:   4320 B
    // total 76128 B -> 2 blocks/CU, 32 waves/CU

    const int tid = threadIdx.x;

    // XCD swizzle: each XCD owns 32 consecutive semantic tiles (a 512x128
    // band of one image) so halo re-reads hit that XCD's own L2.
    const int h    = blockIdx.x;            // 0..2047
    const int sg   = h >> 8;                // supergroup of 256
    const int xcd  = h & 7;
    const int slot = (h >> 3) & 31;
    const int sem  = (sg << 8) + (xcd << 5) + slot;

    const int bx = sem & (GX - 1);
    const int by = (sem >> 3) & (GY - 1);
    const int b  = sem >> 7;
    const int x0 = bx * TX;
    const int y0 = by * TY;

    const size_t plane = (size_t)Hc * Wc;
    const float* src = logits + (size_t)b * NC * plane;

    // Stage the calibration table (1080 floats; threads 0..1079, one each).
    if (tid < NC * NNB * NPB) sVF[tid] = vf[tid];

    // ---- Phase 1: softmax for every halo pixel.
    // Task i covers halo pixel (ly,lx) = (i/66, i%66). Thread handles
    // i = tid, tid+1024 (always valid: 2047 < 2244) and, for tid<196,
    // i = tid+2048. ALL global loads are issued up front (16-24 per
    // thread, clamped addresses; OOB pixels predicated to zero on the
    // LDS write) so one memory latency is paid instead of 2-3, and
    // task-0 compute overlaps task-1/2 loads still in flight.
    int ly_[3], lx_[3];
    bool img_[3];
    const float* ptr_[3];
    const bool has2 = tid < (NHALO - 2 * NT);   // tid < 196

    #pragma unroll
    for (int t = 0; t < 3; t++) {
        const int i  = tid + t * NT;
        const int ly = (int)((unsigned)i / (unsigned)HX);
        const int lx = i - ly * HX;
        const int gy = y0 + ly - 1;
        const int gx = x0 + lx - 1;
        ly_[t]  = ly;
        lx_[t]  = lx;
        img_[t] = ((unsigned)gy < (unsigned)Hc) && ((unsigned)gx < (unsigned)Wc);
        const int gyc = gy < 0 ? 0 : (gy > Hc - 1 ? Hc - 1 : gy);
        const int gxc = gx < 0 ? 0 : (gx > Wc - 1 ? Wc - 1 : gx);
        ptr_[t] = src + (size_t)gyc * Wc + gxc;
    }

    float v0[NC], v1[NC], v2[NC];
    #pragma unroll
    for (int c = 0; c < NC; c++) v0[c] = ptr_[0][(size_t)c * plane];
    #pragma unroll
    for (int c = 0; c < NC; c++) v1[c] = ptr_[1][(size_t)c * plane];
    if (has2) {
        #pragma unroll
        for (int c = 0; c < NC; c++) v2[c] = ptr_[2][(size_t)c * plane];
    }

    // Softmax per task: per-pixel fp32 op ORDER byte-identical to the
    // validated pipeline (fmax chain, exp_f32_cr, sequential sum, rcp64,
    // per-class double-mul). OOB pixels write 0 (reduce_window zero-pad).
    {
        float* v = v0;
        float m = v[0];
        #pragma unroll
        for (int c = 1; c < NC; c++) m = fmaxf(m, v[c]);
        float S = 0.0f;
        #pragma unroll
        for (int c = 0; c < NC; c++) { v[c] = exp_f32_cr(v[c] - m); S = S + v[c]; }
        double rS = rcp64(S);
        #pragma unroll
        for (int c = 0; c < NC; c++)
            sP[c][ly_[0]][lx_[0]] = img_[0] ? (float)((double)v[c] * rS) : 0.0f;
    }
    {
        float* v = v1;
        float m = v[0];
        #pragma unroll
        for (int c = 1; c < NC; c++) m = fmaxf(m, v[c]);
        float S = 0.0f;
        #pragma unroll
        for (int c = 0; c < NC; c++) { v[c] = exp_f32_cr(v[c] - m); S = S + v[c]; }
        double rS = rcp64(S);
        #pragma unroll
        for (int c = 0; c < NC; c++)
            sP[c][ly_[1]][lx_[1]] = img_[1] ? (float)((double)v[c] * rS) : 0.0f;
    }
    if (has2) {
        float* v = v2;
        float m = v[0];
        #pragma unroll
        for (int c = 1; c < NC; c++) m = fmaxf(m, v[c]);
        float S = 0.0f;
        #pragma unroll
        for (int c = 0; c < NC; c++) { v[c] = exp_f32_cr(v[c] - m); S = S + v[c]; }
        double rS = rcp64(S);
        #pragma unroll
        for (int c = 0; c < NC; c++)
            sP[c][ly_[2]][lx_[2]] = img_[2] ? (float)((double)v[c] * rS) : 0.0f;
    }
    __syncthreads();

    // ---- Phase 2: each thread -> 2 horizontally adjacent outputs.
    // lx2 even + row stride 66 dwords (even) -> all window reads are
    // 8B-aligned f32x2 (ds_read_b64), output stores are dwordx2.
    const int lx2 = (tid & 31) * 2;         // 0,2,..,62
    const int oy  = tid >> 5;               // 0..31
    const int gx2 = x0 + lx2;
    const int gy  = y0 + oy;

    const double C9 = 0.1111111111111111111;    // nearest double to 1/9

    float calL[NC], calR[NC];
    float s0 = 0.0f, s1 = 0.0f;
    #pragma unroll
    for (int c = 0; c < NC; c++) {
        const float* base = &sP[c][oy][lx2];    // halo cols lx2..lx2+3, rows oy..oy+2
        f32x2 u0 = *(const f32x2*)(base);
        f32x2 w0 = *(const f32x2*)(base + 2);
        f32x2 u1 = *(const f32x2*)(base + HX);
        f32x2 w1 = *(const f32x2*)(base + HX + 2);
        f32x2 u2 = *(const f32x2*)(base + 2 * HX);
        f32x2 w2 = *(const f32x2*)(base + 2 * HX + 2);
        // Strict left-to-right sequential add chains (row-major (dy,dx)
        // order) — reassociation would flip bins, order is sacred.
        // Left output window: cols {0,1,2}; right output: cols {1,2,3}.
        float a0 = ((((((((u0.x + u0.y) + w0.x) + u1.x) + u1.y) + w1.x) + u2.x) + u2.y) + w2.x);
        float a1 = ((((((((u0.y + w0.x) + w0.y) + u1.y) + w1.x) + w1.y) + u2.y) + w2.x) + w2.y);

        float nm0 = (float)((double)a0 * C9);   // fl32(a/9) via double mul
        float nm1 = (float)((double)a1 * C9);
        int lb0 = (int)(nm0 * 9.0f);            // trunc == floor (nm >= 0)
        int lb1 = (int)(nm1 * 9.0f);
        lb0 = lb0 > NNB - 1 ? NNB - 1 : lb0;
        lb1 = lb1 > NNB - 1 ? NNB - 1 : lb1;
        int pb0 = (int)(u1.y * 15.0f);          // center of left window
        int pb1 = (int)(w1.x * 15.0f);          // center of right window
        pb0 = pb0 > NPB - 1 ? NPB - 1 : pb0;
        pb1 = pb1 > NPB - 1 ? NPB - 1 : pb1;
        calL[c] = sVF[(c * NNB + lb0) * NPB + pb0];
        calR[c] = sVF[(c * NNB + lb1) * NPB + pb1];
        s0 = s0 + calL[c];                      // sequential class sum
        s1 = s1 + calR[c];
    }
    if (s0 == 0.0f) s0 = 1.0f;
    if (s1 == 0.0f) s1 = 1.0f;

    // Final normalize is NOT bin-critical (bf16-floor comparison): fp32
    // rcp + 1 Newton, rel err ~1e-7 << threshold.
    float q0 = __builtin_amdgcn_rcpf(s0);
    q0 = q0 * fmaf(-s0, q0, 2.0f);
    float q1 = __builtin_amdgcn_rcpf(s1);
    q1 = q1 * fmaf(-s1, q1, 2.0f);

    // Nontemporal stores: output is write-once/never-read — keep it from
    // evicting the L3-resident logits.
    float* dst = out + (size_t)b * NC * plane + (size_t)gy * Wc + gx2;
    #pragma unroll
    for (int c = 0; c < NC; c++) {
        f32x2 o;
        o.x = calL[c] * q0;
        o.y = calR[c] * q1;
        __builtin_nontemporal_store(o, (f32x2*)(dst + (size_t)c * plane));
    }
}

extern "C" void kernel_launch(void* const* d_in, const int* in_sizes, int n_in,
                              void* d_out, int out_size, void* d_ws, size_t ws_size,
                              hipStream_t stream) {
    const float* logits = (const float*)d_in[0];
    const float* vf     = (const float*)d_in[1];
    float* out          = (float*)d_out;

    nectar_kernel<<<dim3(NBLK), dim3(NT), 0, stream>>>(logits, vf, out);
}